// Round 4
// baseline (221.464 us; speedup 1.0000x reference)
//
#include <hip/hip_runtime.h>
#include <hip/hip_bf16.h>

#define NN 20000
#define NE 160000
#define CPB 8    // slots per (bucket,half) -> 64*2*8 = 1024 blocks = 4/CU resident

typedef __attribute__((ext_vector_type(8))) short short8;
typedef __attribute__((ext_vector_type(4))) float floatx4;

__device__ __forceinline__ short f2bf(float f) {
    unsigned u = __float_as_uint(f);
    u += 0x7fff + ((u >> 16) & 1);   // RNE
    return (short)(u >> 16);
}
__device__ __forceinline__ float bf2f(unsigned short u) {
    return __uint_as_float(((unsigned)u) << 16);
}

// ---------------- K1: anchor histogram + per-row rank ----------------
__global__ void k_count(const float* __restrict__ pseudo, const int* __restrict__ ei,
                        int* __restrict__ cntp, int* __restrict__ degi,
                        int* __restrict__ anchor, int* __restrict__ rposa) {
    __shared__ int lh[64];
    int tid = threadIdx.x;
    if (tid < 64) lh[tid] = 0;
    __syncthreads();
    int e = blockIdx.x * 256 + tid;
    if (e < NE) {
        float p0 = pseudo[e*3+0], p1 = pseudo[e*3+1], p2 = pseudo[e*3+2];
        int v0 = min(3, max(0, (int)floorf(p0 * 4.f)));
        int v1 = min(3, max(0, (int)floorf(p1 * 4.f)));
        int v2 = min(3, max(0, (int)floorf(p2 * 4.f)));
        int a = v0 + 4*v1 + 16*v2;
        anchor[e] = a;
        atomicAdd(&lh[a], 1);
        rposa[e] = atomicAdd(&degi[ei[e]], 1);   // rank within destination row
    }
    __syncthreads();
    if (tid < 64 && lh[tid]) atomicAdd(&cntp[tid*32], lh[tid]);
}

// ---------------- K2: both scans in one dispatch ----------------
// block 0: 64-bin exclusive scan  |  block 1: rowoff[NN+1] from degi
__global__ void k_scans(const int* __restrict__ cntp, int* __restrict__ off,
                        const int* __restrict__ degi, int* __restrict__ rowoff) {
    if (blockIdx.x == 0) {
        if (threadIdx.x == 0) {
            int acc = 0;
            for (int i = 0; i < 64; i++) { off[i] = acc; acc += cntp[i*32]; }
            off[64] = acc;
        }
        return;
    }
    __shared__ int ps[256];
    int t = threadIdx.x;
    int b0 = t * 79;                      // 256*79 = 20224 >= 20001
    int s = 0;
    for (int i = 0; i < 79; i++) { int idx = b0 + i; if (idx < NN) s += degi[idx]; }
    ps[t] = s;
    __syncthreads();
    if (t == 0) { int a = 0; for (int i = 0; i < 256; i++) { int v = ps[i]; ps[i] = a; a += v; } }
    __syncthreads();
    int run = ps[t];
    for (int i = 0; i < 79; i++) {
        int idx = b0 + i;
        if (idx <= NN) rowoff[idx] = run;
        if (idx < NN) run += degi[idx];
    }
}

// ---------------- K3: scatter edge ids into anchor buckets ----------------
__global__ void k_scatter(const int* __restrict__ anchor, const int* __restrict__ off,
                          int* __restrict__ curp, int* __restrict__ eidx) {
    __shared__ int lh[64];
    __shared__ int gb[64];
    int tid = threadIdx.x;
    if (tid < 64) lh[tid] = 0;
    __syncthreads();
    int e = blockIdx.x * 256 + tid;
    int a = 0, r = 0;
    if (e < NE) {
        a = anchor[e];
        r = atomicAdd(&lh[a], 1);
    }
    __syncthreads();
    if (tid < 64) gb[tid] = lh[tid] ? atomicAdd(&curp[tid*32], lh[tid]) : 0;
    __syncthreads();
    if (e < NE) eidx[off[a] + gb[a] + r] = e;
}

// ---------------- K3.5: pre-permute W into MFMA B-fragment order ----------------
// layout: wf[b*32768 + nt*8192 + t*512 + l*8 + j]; k = 32t+(l>>4)*8+j; n = nt*16+(l&15)
// coalesced 2B stores (consecutive lanes -> consecutive f), reads L1-resident per s.
__global__ void k_wfrag(const float* __restrict__ w, unsigned short* __restrict__ wf) {
    int b = blockIdx.x;
    int b0 = b & 3, b1 = (b >> 2) & 3, b2 = (b >> 4) & 3;
    int wbase = b0 + 5*b1 + 25*b2;
    int tid = threadIdx.x;
    #pragma unroll 1
    for (int s = 0; s < 8; s++) {
        int widx = wbase + (s & 1) + 5*((s >> 1) & 1) + 25*((s >> 2) & 1);
        const float* wm = w + widx*4096;
        #pragma unroll
        for (int idx = tid; idx < 4096; idx += 256) {
            int nt = idx >> 10;
            int tl = (idx >> 9) & 1;
            int t  = 2*s + tl;
            int lj = idx & 511;
            int l = lj >> 3, j = lj & 7;
            int i = 32*tl + (l >> 4)*8 + j;
            int n = nt*16 + (l & 15);
            wf[b*32768 + nt*8192 + t*512 + lj] = (unsigned short)f2bf(wm[i*64 + n]);
        }
    }
}

// ---------------- K4: main bucketed spline GEMM (col-split halves) ----------------
#define LOADSTAGE(P, E_, COL_, PA_, PB_, PC_, A0_, A1_, B0_, B1_)                 \
    {                                                                              \
        int m_ = cnt - (P);                                                        \
        bool valid_ = er < m_;                                                     \
        E_ = eidx[base + (P) + (valid_ ? er : 0)];                                 \
        COL_ = ei[NE + E_];                                                        \
        PA_ = pseudo[E_*3+0]; PB_ = pseudo[E_*3+1]; PC_ = pseudo[E_*3+2];          \
        const float4* xr_ = (const float4*)(x + COL_*64 + g*8);                    \
        A0_ = xr_[0]; A1_ = xr_[1];                                                \
        const float4* xr2_ = (const float4*)(x + COL_*64 + 32 + g*8);              \
        B0_ = xr2_[0]; B1_ = xr2_[1];                                              \
    }

__global__ __launch_bounds__(256, 4)
void k_main(const float* __restrict__ x, const int* __restrict__ ei,
            const float* __restrict__ pseudo, const unsigned short* __restrict__ wfrag_g,
            const int* __restrict__ off, const int* __restrict__ eidx,
            const int* __restrict__ rowoff, const int* __restrict__ rposa,
            unsigned short* __restrict__ msg) {
    __shared__ unsigned short wf[16384];   // 32 KB: half of the bucket's B fragments
    int bh = blockIdx.x & 127;             // (bucket, half) in low bits -> same XCD for all slots
    int b = bh >> 1, h = bh & 1;
    int slot = blockIdx.x >> 7;            // 0..CPB-1

    {
        const int4* src = (const int4*)(wfrag_g + b*32768 + h*16384);
        int4* dst = (int4*)wf;
        for (int i = threadIdx.x; i < 2048; i += 256) dst[i] = src[i];
    }
    __syncthreads();

    int base = off[b];
    int cnt  = off[b+1] - base;
    int wv = threadIdx.x >> 6;
    int l  = threadIdx.x & 63;
    int er = l & 15;
    int g  = l >> 4;

    const int STRIDE = CPB * 64;
    int p = slot*64 + wv*16;
    if (p >= cnt) return;

    int eC, colC; float paC, pbC, pcC; float4 xa0, xa1, xb0, xb1;
    LOADSTAGE(p, eC, colC, paC, pbC, pcC, xa0, xa1, xb0, xb1);

    for (; p < cnt; p += STRIDE) {
        int pn = p + STRIDE;
        int eN = 0, colN = 0; float paN = 0, pbN = 0, pcN = 0;
        float4 na0, na1, nb0, nb1;
        if (pn < cnt) LOADSTAGE(pn, eN, colN, paN, pbN, pcN, na0, na1, nb0, nb1);

        int m = min(16, cnt - p);
        bool valid = er < m;

        float va = paC * 4.f, vb = pbC * 4.f, vc = pcC * 4.f;
        float f0 = va - floorf(va);
        float f1 = vb - floorf(vb);
        float f2 = vc - floorf(vc);
        float fb[8];
        #pragma unroll
        for (int s = 0; s < 8; s++) {
            float t0 = (s & 1) ? f0 : 1.f - f0;
            float t1 = (s & 2) ? f1 : 1.f - f1;
            float t2 = (s & 4) ? f2 : 1.f - f2;
            fb[s] = valid ? t0 * t1 * t2 : 0.f;
        }

        float xA[8], xB[8];
        xA[0]=xa0.x; xA[1]=xa0.y; xA[2]=xa0.z; xA[3]=xa0.w;
        xA[4]=xa1.x; xA[5]=xa1.y; xA[6]=xa1.z; xA[7]=xa1.w;
        xB[0]=xb0.x; xB[1]=xb0.y; xB[2]=xb0.z; xB[3]=xb0.w;
        xB[4]=xb1.x; xB[5]=xb1.y; xB[6]=xb1.z; xB[7]=xb1.w;

        floatx4 acc[2];
        acc[0] = (floatx4){0.f, 0.f, 0.f, 0.f};
        acc[1] = (floatx4){0.f, 0.f, 0.f, 0.f};

        #pragma unroll
        for (int t = 0; t < 16; t++) {
            const int s = t >> 1;
            const float* xf = (t & 1) ? xB : xA;
            short8 afrag;
            #pragma unroll
            for (int j = 0; j < 8; j++) afrag[j] = f2bf(fb[s] * xf[j]);
            #pragma unroll
            for (int nt = 0; nt < 2; nt++) {
                short8 bfrag = *(const short8*)&wf[(nt*16 + t)*512 + l*8];
                acc[nt] = __builtin_amdgcn_mfma_f32_16x16x32_bf16(afrag, bfrag, acc[nt], 0, 0, 0);
            }
        }

        // store row-grouped bf16 messages: D row = g*4+r (edge), col = h*32 + nt*16 + (l&15)
        #pragma unroll
        for (int r = 0; r < 4; r++) {
            int mr = g*4 + r;
            if (mr < m) {
                int em = eidx[base + p + mr];
                int rw = ei[em];
                int dst = rowoff[rw] + rposa[em];
                unsigned short* mp = msg + (size_t)dst*64 + h*32 + (l & 15);
                mp[0]  = (unsigned short)f2bf(acc[0][r]);
                mp[16] = (unsigned short)f2bf(acc[1][r]);
            }
        }

        eC = eN; colC = colN; paC = paN; pbC = pbN; pcC = pcN;
        xa0 = na0; xa1 = na1; xb0 = nb0; xb1 = nb1;
    }
}

// ---------------- K5: out = rowmean(msg) + x@root + bias ----------------
__global__ void k_final2(const float* __restrict__ x, const float* __restrict__ root,
                         const float* __restrict__ bias, const unsigned short* __restrict__ msg,
                         const int* __restrict__ rowoff, float* __restrict__ out) {
    __shared__ float rs[4096];
    for (int i = threadIdx.x; i < 4096; i += 256) rs[i] = root[i];
    __syncthreads();
    int n = blockIdx.x * 4 + (threadIdx.x >> 6);
    int o = threadIdx.x & 63;
    int b0 = rowoff[n], b1 = rowoff[n+1];
    float v = 0.f;
    for (int j = b0; j < b1; j++) v += bf2f(msg[(size_t)j*64 + o]);
    v *= 1.0f / (float)max(b1 - b0, 1);
    v += bias[o];
    const float* xr = x + n*64;
    #pragma unroll 8
    for (int i = 0; i < 64; i++) v += xr[i] * rs[i*64 + o];
    out[n*64 + o] = v;
}

extern "C" void kernel_launch(void* const* d_in, const int* in_sizes, int n_in,
                              void* d_out, int out_size, void* d_ws, size_t ws_size,
                              hipStream_t stream) {
    const float* x      = (const float*)d_in[0];
    const int*   ei     = (const int*)d_in[1];
    const float* pseudo = (const float*)d_in[2];
    const float* weight = (const float*)d_in[3];
    const float* root   = (const float*)d_in[4];
    const float* bias   = (const float*)d_in[5];
    float* out = (float*)d_out;
    char* ws = (char*)d_ws;

    unsigned short* msg    = (unsigned short*)(ws + 0);        // 20,480,000 B
    int*            degi   = (int*)(ws + 20480000);            //     80,000 B
    int*            cntp   = (int*)(ws + 20560000);            //      8,192 B
    int*            curp   = (int*)(ws + 20568192);            //      8,192 B
    int*            off    = (int*)(ws + 20576384);            //        512 B
    int*            rowoff = (int*)(ws + 20576896);            //     80,128 B
    int*            anchor = (int*)(ws + 20657024);            //    640,000 B
    int*            rposa  = (int*)(ws + 21297024);            //    640,000 B
    int*            eidx   = (int*)(ws + 21937024);            //    640,000 B
    unsigned short* wfg    = (unsigned short*)(ws + 22577024); //  4,194,304 B -> total ~26.8 MB

    // zero degi + cntp + curp (contiguous)
    hipMemsetAsync(ws + 20480000, 0, 96384, stream);

    k_count  <<<(NE + 255)/256, 256, 0, stream>>>(pseudo, ei, cntp, degi, anchor, rposa);
    k_scans  <<<2, 256, 0, stream>>>(cntp, off, degi, rowoff);
    k_scatter<<<(NE + 255)/256, 256, 0, stream>>>(anchor, off, curp, eidx);
    k_wfrag  <<<64, 256, 0, stream>>>(weight, wfg);
    k_main   <<<64*2*CPB, 256, 0, stream>>>(x, ei, pseudo, wfg, off, eidx, rowoff, rposa, msg);
    k_final2 <<<NN/4, 256, 0, stream>>>(x, root, bias, msg, rowoff, out);
}

// Round 5
// 171.544 us; speedup vs baseline: 1.2910x; 1.2910x over previous
//
#include <hip/hip_runtime.h>
#include <hip/hip_bf16.h>

#define NN 20000
#define NE 160000
#define CPB 8    // slots per bucket -> 64*8 = 512 blocks = 2/CU (LDS-limited)

typedef __attribute__((ext_vector_type(8))) short short8;
typedef __attribute__((ext_vector_type(4))) float floatx4;

__device__ __forceinline__ unsigned short f2bf(float f) {
    unsigned u = __float_as_uint(f);
    u += 0x7fff + ((u >> 16) & 1);   // RNE
    return (unsigned short)(u >> 16);
}
__device__ __forceinline__ float bf2f(unsigned short u) {
    return __uint_as_float(((unsigned)u) << 16);
}

// ---------------- K1: anchor histogram + per-row rank ----------------
__global__ void k_count(const float* __restrict__ pseudo, const int* __restrict__ ei,
                        int* __restrict__ cntp, int* __restrict__ degi,
                        int* __restrict__ rposa) {
    __shared__ int lh[64];
    int tid = threadIdx.x;
    if (tid < 64) lh[tid] = 0;
    __syncthreads();
    int e = blockIdx.x * 256 + tid;
    if (e < NE) {
        float p0 = pseudo[e*3+0], p1 = pseudo[e*3+1], p2 = pseudo[e*3+2];
        int v0 = min(3, max(0, (int)floorf(p0 * 4.f)));
        int v1 = min(3, max(0, (int)floorf(p1 * 4.f)));
        int v2 = min(3, max(0, (int)floorf(p2 * 4.f)));
        int a = v0 + 4*v1 + 16*v2;
        atomicAdd(&lh[a], 1);
        rposa[e] = atomicAdd(&degi[ei[e]], 1);   // rank within destination row
    }
    __syncthreads();
    if (tid < 64 && lh[tid]) atomicAdd(&cntp[tid*32], lh[tid]);
}

// ---------------- K2: both scans in one dispatch ----------------
__global__ void k_scans(const int* __restrict__ cntp, int* __restrict__ off,
                        const int* __restrict__ degi, int* __restrict__ rowoff) {
    if (blockIdx.x == 0) {
        if (threadIdx.x == 0) {
            int acc = 0;
            for (int i = 0; i < 64; i++) { off[i] = acc; acc += cntp[i*32]; }
            off[64] = acc;
        }
        return;
    }
    __shared__ int ps[256];
    int t = threadIdx.x;
    int b0 = t * 79;                      // 256*79 = 20224 >= 20001
    int s = 0;
    for (int i = 0; i < 79; i++) { int idx = b0 + i; if (idx < NN) s += degi[idx]; }
    ps[t] = s;
    __syncthreads();
    if (t == 0) { int a = 0; for (int i = 0; i < 256; i++) { int v = ps[i]; ps[i] = a; a += v; } }
    __syncthreads();
    int run = ps[t];
    for (int i = 0; i < 79; i++) {
        int idx = b0 + i;
        if (idx <= NN) rowoff[idx] = run;
        if (idx < NN) run += degi[idx];
    }
}

// ---------------- K3: prep — scatter + pre-gather (merged) ----------------
// For each edge: slot i (bucket-ordered), write xg[i] (bf16 x-row), basisg[i][8],
// dsti[i] = final msg destination. k_main then has ZERO dependent gathers.
__global__ void k_prep(const float* __restrict__ x, const int* __restrict__ ei,
                       const float* __restrict__ pseudo, const int* __restrict__ off,
                       int* __restrict__ curp, const int* __restrict__ rowoff,
                       const int* __restrict__ rposa,
                       unsigned short* __restrict__ xg, float* __restrict__ basisg,
                       int* __restrict__ dsti) {
    __shared__ int lh[64];
    __shared__ int gb[64];
    int tid = threadIdx.x;
    if (tid < 64) lh[tid] = 0;
    __syncthreads();
    int e = blockIdx.x * 256 + tid;
    int a = 0, r = 0;
    float p0 = 0.f, p1 = 0.f, p2 = 0.f;
    if (e < NE) {
        p0 = pseudo[e*3+0]; p1 = pseudo[e*3+1]; p2 = pseudo[e*3+2];
        int v0 = min(3, max(0, (int)floorf(p0 * 4.f)));
        int v1 = min(3, max(0, (int)floorf(p1 * 4.f)));
        int v2 = min(3, max(0, (int)floorf(p2 * 4.f)));
        a = v0 + 4*v1 + 16*v2;
        r = atomicAdd(&lh[a], 1);
    }
    __syncthreads();
    if (tid < 64) gb[tid] = lh[tid] ? atomicAdd(&curp[tid*32], lh[tid]) : 0;
    __syncthreads();
    if (e >= NE) return;
    int i = off[a] + gb[a] + r;

    int row = ei[e], col = ei[NE + e];
    dsti[i] = rowoff[row] + rposa[e];

    float va = p0*4.f, vb = p1*4.f, vc = p2*4.f;
    float f0 = va - floorf(va);
    float f1 = vb - floorf(vb);
    float f2 = vc - floorf(vc);
    float* bp = basisg + (size_t)i*8;
    #pragma unroll
    for (int s = 0; s < 8; s++) {
        float t0 = (s & 1) ? f0 : 1.f - f0;
        float t1 = (s & 2) ? f1 : 1.f - f1;
        float t2 = (s & 4) ? f2 : 1.f - f2;
        bp[s] = t0 * t1 * t2;
    }

    const float4* xr = (const float4*)(x + (size_t)col*64);
    unsigned short* xrow = xg + (size_t)i*64;
    #pragma unroll
    for (int q = 0; q < 16; q++) {
        float4 v = xr[q];
        ushort4 pk;
        pk.x = f2bf(v.x); pk.y = f2bf(v.y); pk.z = f2bf(v.z); pk.w = f2bf(v.w);
        *(ushort4*)(xrow + q*4) = pk;   // 8B coalescing-friendly stores
    }
}

// ---------------- K4: main streaming spline GEMM ----------------
// All reads are linear streams (xg/basis/dsti per tile); W permuted into LDS
// inline from global weight (L2/L3-hot). Only the msg store scatters.
__global__ __launch_bounds__(256)
void k_main(const float* __restrict__ weight, const int* __restrict__ off,
            const unsigned short* __restrict__ xg, const float* __restrict__ basisg,
            const int* __restrict__ dsti, unsigned short* __restrict__ msg) {
    __shared__ unsigned short wf[32768];   // 64 KB: B fragments, bucket b
    int b = blockIdx.x & 63;
    int slot = blockIdx.x >> 6;
    int tid = threadIdx.x;

    {   // inline W permute: 8 matrices, coalesced global reads, scattered LDS writes
        int c0 = b & 3, c1 = (b >> 2) & 3, c2 = (b >> 4) & 3;
        int wbase = c0 + 5*c1 + 25*c2;
        #pragma unroll 1
        for (int s = 0; s < 8; s++) {
            int widx = wbase + (s & 1) + 5*((s >> 1) & 1) + 25*((s >> 2) & 1);
            const float* wm = weight + widx*4096;
            #pragma unroll 1
            for (int idx = tid; idx < 4096; idx += 256) {
                int i = idx >> 6, n = idx & 63;       // read wm[idx]: coalesced
                int tl = i >> 5, j = i & 7, gw = (i >> 3) & 3;
                int lw = gw*16 + (n & 15), nt = n >> 4;
                int t = 2*s + tl;
                wf[((nt*16 + t)*64 + lw)*8 + j] = f2bf(wm[idx]);
            }
        }
    }
    __syncthreads();

    int base = off[b];
    int cnt  = off[b+1] - base;
    int wv = tid >> 6;
    int l  = tid & 63;
    int er = l & 15;
    int g  = l >> 4;

    const int STRIDE = CPB * 64;
    int p = slot*64 + wv*16;
    if (p >= cnt) return;

    const unsigned short* xgb = xg + (size_t)base*64;
    const float* bsb = basisg + (size_t)base*8;
    const int* dsb = dsti + base;

#define LOADT(P, XA, XB, B0, B1, DD)                                       \
    {                                                                       \
        const unsigned short* rp_ = xgb + (size_t)((P) + er)*64;            \
        XA = *(const short8*)(rp_ + g*8);                                   \
        XB = *(const short8*)(rp_ + 32 + g*8);                              \
        const float4* bp_ = (const float4*)(bsb + (size_t)((P) + er)*8);    \
        B0 = bp_[0]; B1 = bp_[1];                                           \
        DD = dsb[(P) + er];                                                 \
    }

    short8 cxa, cxb; float4 cb0, cb1; int cdst;
    LOADT(p, cxa, cxb, cb0, cb1, cdst);

    for (; p < cnt; p += STRIDE) {
        int pn = p + STRIDE;
        short8 nxa, nxb; float4 nb0, nb1; int ndst = 0;
        if (pn < cnt) LOADT(pn, nxa, nxb, nb0, nb1, ndst);

        float fb[8] = {cb0.x, cb0.y, cb0.z, cb0.w, cb1.x, cb1.y, cb1.z, cb1.w};
        float xA[8], xB[8];
        #pragma unroll
        for (int j = 0; j < 8; j++) {
            xA[j] = bf2f((unsigned short)cxa[j]);
            xB[j] = bf2f((unsigned short)cxb[j]);
        }

        floatx4 acc[4];
        #pragma unroll
        for (int nt = 0; nt < 4; nt++) acc[nt] = (floatx4){0.f, 0.f, 0.f, 0.f};

        #pragma unroll
        for (int t = 0; t < 16; t++) {
            const int s = t >> 1;
            const float* xf = (t & 1) ? xB : xA;
            short8 afrag;
            #pragma unroll
            for (int j = 0; j < 8; j++) afrag[j] = (short)f2bf(fb[s] * xf[j]);
            #pragma unroll
            for (int nt = 0; nt < 4; nt++) {
                short8 bfrag = *(const short8*)&wf[((nt*16 + t)*64 + l)*8];
                acc[nt] = __builtin_amdgcn_mfma_f32_16x16x32_bf16(afrag, bfrag, acc[nt], 0, 0, 0);
            }
        }

        // store: D row = g*4+r (edge slot), col = nt*16 + (l&15)
        #pragma unroll
        for (int r = 0; r < 4; r++) {
            int mr = g*4 + r;
            int dstr = __shfl(cdst, mr);
            if (p + mr < cnt) {
                unsigned short* mp = msg + (size_t)dstr*64 + (l & 15);
                mp[0]  = f2bf(acc[0][r]);
                mp[16] = f2bf(acc[1][r]);
                mp[32] = f2bf(acc[2][r]);
                mp[48] = f2bf(acc[3][r]);
            }
        }

        cxa = nxa; cxb = nxb; cb0 = nb0; cb1 = nb1; cdst = ndst;
    }
#undef LOADT
}

// ---------------- K5: out = rowmean(msg) + x@root + bias ----------------
__global__ void k_final2(const float* __restrict__ x, const float* __restrict__ root,
                         const float* __restrict__ bias, const unsigned short* __restrict__ msg,
                         const int* __restrict__ rowoff, float* __restrict__ out) {
    __shared__ float rs[4096];
    for (int i = threadIdx.x; i < 4096; i += 256) rs[i] = root[i];
    __syncthreads();
    int n = blockIdx.x * 4 + (threadIdx.x >> 6);
    int o = threadIdx.x & 63;
    int b0 = rowoff[n], b1 = rowoff[n+1];
    float v = 0.f;
    for (int j = b0; j < b1; j++) v += bf2f(msg[(size_t)j*64 + o]);
    v *= 1.0f / (float)max(b1 - b0, 1);
    v += bias[o];
    const float* xr = x + n*64;
    #pragma unroll 8
    for (int i = 0; i < 64; i++) v += xr[i] * rs[i*64 + o];
    out[n*64 + o] = v;
}

extern "C" void kernel_launch(void* const* d_in, const int* in_sizes, int n_in,
                              void* d_out, int out_size, void* d_ws, size_t ws_size,
                              hipStream_t stream) {
    const float* x      = (const float*)d_in[0];
    const int*   ei     = (const int*)d_in[1];
    const float* pseudo = (const float*)d_in[2];
    const float* weight = (const float*)d_in[3];
    const float* root   = (const float*)d_in[4];
    const float* bias   = (const float*)d_in[5];
    float* out = (float*)d_out;
    char* ws = (char*)d_ws;

    unsigned short* msg    = (unsigned short*)(ws + 0);         // 20,480,000
    unsigned short* xg     = (unsigned short*)(ws + 20480000);  // 20,482,048 (+16 pad rows)
    float*          basisg = (float*)(ws + 40962048);           //  5,120,512 (+16 pad)
    int*            dsti   = (int*)(ws + 46082560);             //    640,064 (+16 pad)
    int*            degi   = (int*)(ws + 46722624);             //     80,000
    int*            cntp   = (int*)(ws + 46802624);             //      8,192
    int*            curp   = (int*)(ws + 46810816);             //      8,192
    int*            off    = (int*)(ws + 46819008);             //        512
    int*            rowoff = (int*)(ws + 46819520);             //     80,128
    int*            rposa  = (int*)(ws + 46899648);             //    640,000  -> ~47.5 MB

    // zero degi + cntp + curp (contiguous block)
    hipMemsetAsync(ws + 46722624, 0, 96384, stream);

    k_count <<<(NE + 255)/256, 256, 0, stream>>>(pseudo, ei, cntp, degi, rposa);
    k_scans <<<2, 256, 0, stream>>>(cntp, off, degi, rowoff);
    k_prep  <<<(NE + 255)/256, 256, 0, stream>>>(x, ei, pseudo, off, curp, rowoff, rposa,
                                                 xg, basisg, dsti);
    k_main  <<<64*CPB, 256, 0, stream>>>(weight, off, xg, basisg, dsti, msg);
    k_final2<<<NN/4, 256, 0, stream>>>(x, root, bias, msg, rowoff, out);
}

// Round 6
// 145.458 us; speedup vs baseline: 1.5225x; 1.1793x over previous
//
#include <hip/hip_runtime.h>
#include <hip/hip_bf16.h>

#define NN 20000
#define NE 160000
#define CPB 10   // slots per (bucket,half): 64*2*10 = 1280 blocks = 5/CU (32KB LDS)

typedef __attribute__((ext_vector_type(8))) short short8;
typedef __attribute__((ext_vector_type(16))) float floatx16;

__device__ __forceinline__ unsigned short f2bf_rn(float f) {
    __hip_bfloat16 h = __float2bfloat16(f);   // compiler pairs into v_cvt_pk_bf16_f32
    return __builtin_bit_cast(unsigned short, h);
}
__device__ __forceinline__ float bf2f(unsigned short u) {
    return __uint_as_float(((unsigned)u) << 16);
}

// ---------------- K1: anchor histogram + per-row rank ----------------
__global__ void k_count(const float* __restrict__ pseudo, const int* __restrict__ ei,
                        int* __restrict__ cntp, int* __restrict__ degi,
                        int* __restrict__ rposa) {
    __shared__ int lh[64];
    int tid = threadIdx.x;
    if (tid < 64) lh[tid] = 0;
    __syncthreads();
    int e = blockIdx.x * 256 + tid;
    if (e < NE) {
        float p0 = pseudo[e*3+0], p1 = pseudo[e*3+1], p2 = pseudo[e*3+2];
        int v0 = min(3, max(0, (int)floorf(p0 * 4.f)));
        int v1 = min(3, max(0, (int)floorf(p1 * 4.f)));
        int v2 = min(3, max(0, (int)floorf(p2 * 4.f)));
        int a = v0 + 4*v1 + 16*v2;
        atomicAdd(&lh[a], 1);
        rposa[e] = atomicAdd(&degi[ei[e]], 1);
    }
    __syncthreads();
    if (tid < 64 && lh[tid]) atomicAdd(&cntp[tid*32], lh[tid]);
}

// ---------------- K2: both scans in one dispatch ----------------
__global__ void k_scans(const int* __restrict__ cntp, int* __restrict__ off,
                        const int* __restrict__ degi, int* __restrict__ rowoff) {
    if (blockIdx.x == 0) {
        if (threadIdx.x == 0) {
            int acc = 0;
            for (int i = 0; i < 64; i++) { off[i] = acc; acc += cntp[i*32]; }
            off[64] = acc;
        }
        return;
    }
    __shared__ int ps[256];
    int t = threadIdx.x;
    int b0 = t * 79;
    int s = 0;
    for (int i = 0; i < 79; i++) { int idx = b0 + i; if (idx < NN) s += degi[idx]; }
    ps[t] = s;
    __syncthreads();
    if (t == 0) { int a = 0; for (int i = 0; i < 256; i++) { int v = ps[i]; ps[i] = a; a += v; } }
    __syncthreads();
    int run = ps[t];
    for (int i = 0; i < 79; i++) {
        int idx = b0 + i;
        if (idx <= NN) rowoff[idx] = run;
        if (idx < NN) run += degi[idx];
    }
}

// ---------------- K3: prep (edge blocks) + W-fragment permute (tail blocks) ----------------
// blocks [0,625): per-edge scatter + x pre-gather (bf16) + basis + dst index.
// blocks [625,753): bh = blk-625: permute weight into 32x32x16 B-fragment order:
//   wfg[bh*16384 + t*512 + l*8 + j] = Wcat[k=16t+(l>>5)*8+j][n=h*32+(l&31)], bf16.
__global__ void k_prep(const float* __restrict__ x, const int* __restrict__ ei,
                       const float* __restrict__ pseudo, const int* __restrict__ off,
                       int* __restrict__ curp, const int* __restrict__ rowoff,
                       const int* __restrict__ rposa, const float* __restrict__ weight,
                       unsigned short* __restrict__ xg, float* __restrict__ basisg,
                       int* __restrict__ dsti, unsigned short* __restrict__ wfg) {
    if (blockIdx.x >= 625) {
        int bh = blockIdx.x - 625;
        int b = bh >> 1, h = bh & 1;
        int wbase = (b & 3) + 5*((b >> 2) & 3) + 25*((b >> 4) & 3);
        int t = threadIdx.x >> 3, lg = threadIdx.x & 7;
        int s = t >> 2;
        int widx = wbase + (s & 1) + 5*((s >> 1) & 1) + 25*((s >> 2) & 1);
        const float* wm = weight + widx*4096 + (16*(t & 3))*64;
        unsigned short tmp[64];
        #pragma unroll
        for (int ll = 0; ll < 8; ll++) {
            int l = lg*8 + ll;
            int ib = (l >> 5) * 8;
            int n = h*32 + (l & 31);
            #pragma unroll
            for (int j = 0; j < 8; j++)
                tmp[ll*8 + j] = f2bf_rn(wm[(ib + j)*64 + n]);
        }
        unsigned short* dstp = wfg + bh*16384 + t*512 + lg*64;
        #pragma unroll
        for (int c = 0; c < 8; c++)
            *(short8*)(dstp + c*8) = *(const short8*)(tmp + c*8);
        return;
    }

    __shared__ int lh[64];
    __shared__ int gb[64];
    int tid = threadIdx.x;
    if (tid < 64) lh[tid] = 0;
    __syncthreads();
    int e = blockIdx.x * 256 + tid;
    int a = 0, r = 0;
    float p0 = 0.f, p1 = 0.f, p2 = 0.f;
    if (e < NE) {
        p0 = pseudo[e*3+0]; p1 = pseudo[e*3+1]; p2 = pseudo[e*3+2];
        int v0 = min(3, max(0, (int)floorf(p0 * 4.f)));
        int v1 = min(3, max(0, (int)floorf(p1 * 4.f)));
        int v2 = min(3, max(0, (int)floorf(p2 * 4.f)));
        a = v0 + 4*v1 + 16*v2;
        r = atomicAdd(&lh[a], 1);
    }
    __syncthreads();
    if (tid < 64) gb[tid] = lh[tid] ? atomicAdd(&curp[tid*32], lh[tid]) : 0;
    __syncthreads();
    if (e >= NE) return;
    int i = off[a] + gb[a] + r;

    int row = ei[e], col = ei[NE + e];
    dsti[i] = rowoff[row] + rposa[e];

    float va = p0*4.f, vb = p1*4.f, vc = p2*4.f;
    float f0 = va - floorf(va);
    float f1 = vb - floorf(vb);
    float f2 = vc - floorf(vc);
    float* bp = basisg + i*8;
    #pragma unroll
    for (int s = 0; s < 8; s++) {
        float t0 = (s & 1) ? f0 : 1.f - f0;
        float t1 = (s & 2) ? f1 : 1.f - f1;
        float t2 = (s & 4) ? f2 : 1.f - f2;
        bp[s] = t0 * t1 * t2;
    }

    const float4* xr = (const float4*)(x + col*64);
    unsigned short* xrow = xg + i*64;
    #pragma unroll
    for (int q = 0; q < 16; q++) {
        float4 v = xr[q];
        ushort4 pk;
        pk.x = f2bf_rn(v.x); pk.y = f2bf_rn(v.y); pk.z = f2bf_rn(v.z); pk.w = f2bf_rn(v.w);
        *(ushort4*)(xrow + q*4) = pk;
    }
}

// ---------------- K4: main streaming spline GEMM, 32x32x16 MFMA, col-split ----------------
__global__ __launch_bounds__(256)
void k_main(const unsigned short* __restrict__ wfg, const int* __restrict__ off,
            const unsigned short* __restrict__ xg, const float* __restrict__ basisg,
            const int* __restrict__ dsti, unsigned short* __restrict__ msg) {
    __shared__ unsigned short wf[16384];   // 32 KB: B fragments for (bucket, half)
    int bh = blockIdx.x & 127;
    int b = bh >> 1, h = bh & 1;
    int slot = blockIdx.x >> 7;            // 0..CPB-1

    {   // linear conflict-free 32KB fill
        const int4* src = (const int4*)(wfg + bh*16384);
        int4* dst = (int4*)wf;
        #pragma unroll
        for (int i = 0; i < 8; i++) dst[i*256 + threadIdx.x] = src[i*256 + threadIdx.x];
    }
    __syncthreads();

    int base = off[b];
    int cnt  = off[b+1] - base;
    int wv = threadIdx.x >> 6;
    int l  = threadIdx.x & 63;
    int er = l & 31;                       // edge slot within 32-edge tile
    int kh = l >> 5;                       // k-half

    const unsigned short* xgb = xg + base*64 + kh*8;
    const float*          bsb = basisg + base*8;
    const int*            dsb = dsti + base;

    for (int p = slot*128 + wv*32; p < cnt; p += CPB*128) {
        int q = p + er;
        bool valid = q < cnt;
        int qc = valid ? q : cnt - 1;

        // x row -> f32 (4 interleaved 8-channel chunks for this k-half)
        float xf[4][8];
        #pragma unroll
        for (int m2 = 0; m2 < 4; m2++) {
            short8 xs = *(const short8*)(xgb + qc*64 + m2*16);
            #pragma unroll
            for (int j = 0; j < 8; j++) xf[m2][j] = bf2f((unsigned short)xs[j]);
        }
        float4 fb0 = *(const float4*)(bsb + qc*8);
        float4 fb1 = *(const float4*)(bsb + qc*8 + 4);
        float fb[8] = {fb0.x, fb0.y, fb0.z, fb0.w, fb1.x, fb1.y, fb1.z, fb1.w};
        if (!valid) {
            #pragma unroll
            for (int s = 0; s < 8; s++) fb[s] = 0.f;
        }
        int dst = dsb[qc];

        floatx16 acc;
        #pragma unroll
        for (int i = 0; i < 16; i++) acc[i] = 0.f;

        #pragma unroll
        for (int t = 0; t < 32; t++) {
            const int s = t >> 2, sub = t & 3;
            short8 afrag;
            #pragma unroll
            for (int j = 0; j < 8; j++)
                afrag[j] = (short)f2bf_rn(fb[s] * xf[sub][j]);
            short8 bfrag = *(const short8*)&wf[t*512 + l*8];
            acc = __builtin_amdgcn_mfma_f32_32x32x16_bf16(afrag, bfrag, acc, 0, 0, 0);
        }

        // D: col = l&31 (-> msg col h*32+er'), row = (r&3) + 8*(r>>2) + 4*kh (edge slot)
        #pragma unroll
        for (int r = 0; r < 16; r++) {
            int row = (r & 3) + 8*(r >> 2) + 4*kh;
            int dstr = __shfl(dst, row);
            if (p + row < cnt)
                msg[dstr*64 + h*32 + er] = f2bf_rn(acc[r]);
        }
    }
}

// ---------------- K5: out = rowmean(msg) + x@root + bias ----------------
__global__ void k_final2(const float* __restrict__ x, const float* __restrict__ root,
                         const float* __restrict__ bias, const unsigned short* __restrict__ msg,
                         const int* __restrict__ rowoff, float* __restrict__ out) {
    __shared__ float rs[4096];
    for (int i = threadIdx.x; i < 4096; i += 256) rs[i] = root[i];
    __syncthreads();
    int n = blockIdx.x * 4 + (threadIdx.x >> 6);
    int o = threadIdx.x & 63;
    int b0 = rowoff[n], b1 = rowoff[n+1];
    float v = 0.f;
    for (int j = b0; j < b1; j++) v += bf2f(msg[j*64 + o]);
    v *= 1.0f / (float)max(b1 - b0, 1);
    v += bias[o];
    const float* xr = x + n*64;
    #pragma unroll 8
    for (int i = 0; i < 64; i++) v += xr[i] * rs[i*64 + o];
    out[n*64 + o] = v;
}

extern "C" void kernel_launch(void* const* d_in, const int* in_sizes, int n_in,
                              void* d_out, int out_size, void* d_ws, size_t ws_size,
                              hipStream_t stream) {
    const float* x      = (const float*)d_in[0];
    const int*   ei     = (const int*)d_in[1];
    const float* pseudo = (const float*)d_in[2];
    const float* weight = (const float*)d_in[3];
    const float* root   = (const float*)d_in[4];
    const float* bias   = (const float*)d_in[5];
    float* out = (float*)d_out;
    char* ws = (char*)d_ws;

    unsigned short* msg    = (unsigned short*)(ws + 0);         // 20,480,000
    unsigned short* xg     = (unsigned short*)(ws + 20480000);  // 20,480,000
    float*          basisg = (float*)(ws + 40960000);           //  5,120,000
    int*            dsti   = (int*)(ws + 46080000);             //    640,000
    int*            degi   = (int*)(ws + 46720000);             //     80,000
    int*            cntp   = (int*)(ws + 46800000);             //      8,192
    int*            curp   = (int*)(ws + 46808192);             //      8,192
    int*            off    = (int*)(ws + 46816384);             //        512
    int*            rowoff = (int*)(ws + 46816896);             //     80,128
    int*            rposa  = (int*)(ws + 46897024);             //    640,000
    unsigned short* wfg    = (unsigned short*)(ws + 47537024);  //  4,194,304 -> ~51.7 MB

    // zero degi + cntp + curp (contiguous)
    hipMemsetAsync(ws + 46720000, 0, 96384, stream);

    k_count <<<(NE + 255)/256, 256, 0, stream>>>(pseudo, ei, cntp, degi, rposa);
    k_scans <<<2, 256, 0, stream>>>(cntp, off, degi, rowoff);
    k_prep  <<<625 + 128, 256, 0, stream>>>(x, ei, pseudo, off, curp, rowoff, rposa,
                                            weight, xg, basisg, dsti, wfg);
    k_main  <<<64*2*CPB, 256, 0, stream>>>(wfg, off, xg, basisg, dsti, msg);
    k_final2<<<NN/4, 256, 0, stream>>>(x, root, bias, msg, rowoff, out);
}

// Round 7
// 109.517 us; speedup vs baseline: 2.0222x; 1.3282x over previous
//
#include <hip/hip_runtime.h>
#include <hip/hip_bf16.h>

#define NN 20000
#define NE 160000
#define CPB 10   // slots per (bucket,half): 64*2*10 = 1280 blocks = 5/CU (32KB LDS)

typedef __attribute__((ext_vector_type(8))) short short8;
typedef __attribute__((ext_vector_type(16))) float floatx16;

__device__ __forceinline__ unsigned short f2bf_rn(float f) {
    __hip_bfloat16 h = __float2bfloat16(f);   // compiler pairs into v_cvt_pk_bf16_f32
    return __builtin_bit_cast(unsigned short, h);
}
__device__ __forceinline__ float bf2f(unsigned short u) {
    return __uint_as_float(((unsigned)u) << 16);
}

// ---------------- K1: anchor histogram + per-row rank ----------------
__global__ void k_count(const float* __restrict__ pseudo, const int* __restrict__ ei,
                        int* __restrict__ cntp, int* __restrict__ degi,
                        int* __restrict__ rposa) {
    __shared__ int lh[64];
    int tid = threadIdx.x;
    if (tid < 64) lh[tid] = 0;
    __syncthreads();
    int e = blockIdx.x * 256 + tid;
    if (e < NE) {
        float p0 = pseudo[e*3+0], p1 = pseudo[e*3+1], p2 = pseudo[e*3+2];
        int v0 = min(3, max(0, (int)floorf(p0 * 4.f)));
        int v1 = min(3, max(0, (int)floorf(p1 * 4.f)));
        int v2 = min(3, max(0, (int)floorf(p2 * 4.f)));
        int a = v0 + 4*v1 + 16*v2;
        atomicAdd(&lh[a], 1);
        rposa[e] = atomicAdd(&degi[ei[e]], 1);
    }
    __syncthreads();
    if (tid < 64 && lh[tid]) atomicAdd(&cntp[tid*32], lh[tid]);
}

// ---------------- K2: both scans in one dispatch ----------------
// block 0: 64-bin scan (trivial). block 1: hierarchical scan of degi[NN] -> rowoff.
// 1024 threads x 20 contiguous ints, int4 loads/stores, shfl-scan.
__global__ void k_scans(const int* __restrict__ cntp, int* __restrict__ off,
                        const int* __restrict__ degi, int* __restrict__ rowoff) {
    if (blockIdx.x == 0) {
        if (threadIdx.x == 0) {
            int acc = 0;
            for (int i = 0; i < 64; i++) { off[i] = acc; acc += cntp[i*32]; }
            off[64] = acc;
        }
        return;
    }
    const int CH = 20;                    // 1024*20 = 20480 >= 20001
    int t = threadIdx.x;
    int base = t * CH;
    int v[CH];
    int tsum = 0;
    #pragma unroll
    for (int i = 0; i < CH; i += 4) {
        int4 q = {0, 0, 0, 0};
        int idx = base + i;
        if (idx + 3 < NN) q = *(const int4*)(degi + idx);
        else {
            q.x = (idx     < NN) ? degi[idx]     : 0;
            q.y = (idx + 1 < NN) ? degi[idx + 1] : 0;
            q.z = (idx + 2 < NN) ? degi[idx + 2] : 0;
            q.w = (idx + 3 < NN) ? degi[idx + 3] : 0;
        }
        v[i] = q.x; v[i+1] = q.y; v[i+2] = q.z; v[i+3] = q.w;
        tsum += q.x + q.y + q.z + q.w;
    }

    int lane = t & 63, wid = t >> 6;      // 16 waves
    int incl = tsum;
    #pragma unroll
    for (int d = 1; d < 64; d <<= 1) {
        int n = __shfl_up(incl, d);
        if (lane >= d) incl += n;
    }
    __shared__ int wsum[16];
    __shared__ int woff[17];
    if (lane == 63) wsum[wid] = incl;
    __syncthreads();
    if (wid == 0 && lane < 16) {
        int w = wsum[lane];
        #pragma unroll
        for (int d = 1; d < 16; d <<= 1) {
            int n = __shfl_up(w, d);
            if (lane >= d) w += n;
        }
        woff[lane + 1] = w;
        if (lane == 0) woff[0] = 0;
    }
    __syncthreads();

    int run = woff[wid] + (incl - tsum);  // exclusive prefix for this thread's chunk
    #pragma unroll
    for (int i = 0; i < CH; i += 4) {
        int4 o;
        o.x = run; run += v[i];
        o.y = run; run += v[i+1];
        o.z = run; run += v[i+2];
        o.w = run; run += v[i+3];
        *(int4*)(rowoff + base + i) = o;  // rowoff sized 20480 ints; idx>NN unused
    }
}

// ---------------- K3: prep (edge blocks) + W-fragment permute (tail blocks) ----------------
__global__ void k_prep(const float* __restrict__ x, const int* __restrict__ ei,
                       const float* __restrict__ pseudo, const int* __restrict__ off,
                       int* __restrict__ curp, const int* __restrict__ rowoff,
                       const int* __restrict__ rposa, const float* __restrict__ weight,
                       unsigned short* __restrict__ xg, float* __restrict__ basisg,
                       int* __restrict__ dsti, unsigned short* __restrict__ wfg) {
    if (blockIdx.x >= 625) {
        int bh = blockIdx.x - 625;
        int b = bh >> 1, h = bh & 1;
        int wbase = (b & 3) + 5*((b >> 2) & 3) + 25*((b >> 4) & 3);
        int t = threadIdx.x >> 3, lg = threadIdx.x & 7;
        int s = t >> 2;
        int widx = wbase + (s & 1) + 5*((s >> 1) & 1) + 25*((s >> 2) & 1);
        const float* wm = weight + widx*4096 + (16*(t & 3))*64;
        unsigned short tmp[64];
        #pragma unroll
        for (int ll = 0; ll < 8; ll++) {
            int l = lg*8 + ll;
            int ib = (l >> 5) * 8;
            int n = h*32 + (l & 31);
            #pragma unroll
            for (int j = 0; j < 8; j++)
                tmp[ll*8 + j] = f2bf_rn(wm[(ib + j)*64 + n]);
        }
        unsigned short* dstp = wfg + bh*16384 + t*512 + lg*64;
        #pragma unroll
        for (int c = 0; c < 8; c++)
            *(short8*)(dstp + c*8) = *(const short8*)(tmp + c*8);
        return;
    }

    __shared__ int lh[64];
    __shared__ int gb[64];
    int tid = threadIdx.x;
    if (tid < 64) lh[tid] = 0;
    __syncthreads();
    int e = blockIdx.x * 256 + tid;
    int a = 0, r = 0;
    float p0 = 0.f, p1 = 0.f, p2 = 0.f;
    if (e < NE) {
        p0 = pseudo[e*3+0]; p1 = pseudo[e*3+1]; p2 = pseudo[e*3+2];
        int v0 = min(3, max(0, (int)floorf(p0 * 4.f)));
        int v1 = min(3, max(0, (int)floorf(p1 * 4.f)));
        int v2 = min(3, max(0, (int)floorf(p2 * 4.f)));
        a = v0 + 4*v1 + 16*v2;
        r = atomicAdd(&lh[a], 1);
    }
    __syncthreads();
    if (tid < 64) gb[tid] = lh[tid] ? atomicAdd(&curp[tid*32], lh[tid]) : 0;
    __syncthreads();
    if (e >= NE) return;
    int i = off[a] + gb[a] + r;

    int row = ei[e], col = ei[NE + e];
    dsti[i] = rowoff[row] + rposa[e];

    float va = p0*4.f, vb = p1*4.f, vc = p2*4.f;
    float f0 = va - floorf(va);
    float f1 = vb - floorf(vb);
    float f2 = vc - floorf(vc);
    float* bp = basisg + i*8;
    #pragma unroll
    for (int s = 0; s < 8; s++) {
        float t0 = (s & 1) ? f0 : 1.f - f0;
        float t1 = (s & 2) ? f1 : 1.f - f1;
        float t2 = (s & 4) ? f2 : 1.f - f2;
        bp[s] = t0 * t1 * t2;
    }

    const float4* xr = (const float4*)(x + col*64);
    unsigned short* xrow = xg + i*64;
    #pragma unroll
    for (int q = 0; q < 16; q++) {
        float4 v = xr[q];
        ushort4 pk;
        pk.x = f2bf_rn(v.x); pk.y = f2bf_rn(v.y); pk.z = f2bf_rn(v.z); pk.w = f2bf_rn(v.w);
        *(ushort4*)(xrow + q*4) = pk;
    }
}

// ---------------- K4: main streaming spline GEMM, 32x32x16 MFMA, col-split ----------------
__global__ __launch_bounds__(256)
void k_main(const unsigned short* __restrict__ wfg, const int* __restrict__ off,
            const unsigned short* __restrict__ xg, const float* __restrict__ basisg,
            const int* __restrict__ dsti, unsigned short* __restrict__ msg) {
    __shared__ unsigned short wf[16384];   // 32 KB: B fragments for (bucket, half)
    int bh = blockIdx.x & 127;
    int b = bh >> 1, h = bh & 1;
    int slot = blockIdx.x >> 7;            // 0..CPB-1

    {   // linear conflict-free 32KB fill
        const int4* src = (const int4*)(wfg + bh*16384);
        int4* dst = (int4*)wf;
        #pragma unroll
        for (int i = 0; i < 8; i++) dst[i*256 + threadIdx.x] = src[i*256 + threadIdx.x];
    }
    __syncthreads();

    int base = off[b];
    int cnt  = off[b+1] - base;
    int wv = threadIdx.x >> 6;
    int l  = threadIdx.x & 63;
    int er = l & 31;                       // edge slot within 32-edge tile
    int kh = l >> 5;                       // k-half

    const unsigned short* xgb = xg + base*64 + kh*8;
    const float*          bsb = basisg + base*8;
    const int*            dsb = dsti + base;

    for (int p = slot*128 + wv*32; p < cnt; p += CPB*128) {
        int q = p + er;
        bool valid = q < cnt;
        int qc = valid ? q : cnt - 1;

        float xf[4][8];
        #pragma unroll
        for (int m2 = 0; m2 < 4; m2++) {
            short8 xs = *(const short8*)(xgb + qc*64 + m2*16);
            #pragma unroll
            for (int j = 0; j < 8; j++) xf[m2][j] = bf2f((unsigned short)xs[j]);
        }
        float4 fb0 = *(const float4*)(bsb + qc*8);
        float4 fb1 = *(const float4*)(bsb + qc*8 + 4);
        float fb[8] = {fb0.x, fb0.y, fb0.z, fb0.w, fb1.x, fb1.y, fb1.z, fb1.w};
        if (!valid) {
            #pragma unroll
            for (int s = 0; s < 8; s++) fb[s] = 0.f;
        }
        int dst = dsb[qc];

        floatx16 acc;
        #pragma unroll
        for (int i = 0; i < 16; i++) acc[i] = 0.f;

        #pragma unroll
        for (int t = 0; t < 32; t++) {
            const int s = t >> 2, sub = t & 3;
            short8 afrag;
            #pragma unroll
            for (int j = 0; j < 8; j++)
                afrag[j] = (short)f2bf_rn(fb[s] * xf[sub][j]);
            short8 bfrag = *(const short8*)&wf[t*512 + l*8];
            acc = __builtin_amdgcn_mfma_f32_32x32x16_bf16(afrag, bfrag, acc, 0, 0, 0);
        }

        // D: col = l&31 (-> msg col h*32+er'), row = (r&3) + 8*(r>>2) + 4*kh
        #pragma unroll
        for (int r = 0; r < 16; r++) {
            int row = (r & 3) + 8*(r >> 2) + 4*kh;
            int dstr = __shfl(dst, row);
            if (p + row < cnt)
                msg[dstr*64 + h*32 + er] = f2bf_rn(acc[r]);
        }
    }
}

// ---------------- K5: out = rowmean(msg) + x@root + bias ----------------
__global__ void k_final2(const float* __restrict__ x, const float* __restrict__ root,
                         const float* __restrict__ bias, const unsigned short* __restrict__ msg,
                         const int* __restrict__ rowoff, float* __restrict__ out) {
    __shared__ float rs[4096];
    for (int i = threadIdx.x; i < 4096; i += 256) rs[i] = root[i];
    __syncthreads();
    int n = blockIdx.x * 4 + (threadIdx.x >> 6);
    int o = threadIdx.x & 63;
    int b0 = rowoff[n], b1 = rowoff[n+1];
    float v = 0.f;
    for (int j = b0; j < b1; j++) v += bf2f(msg[j*64 + o]);
    v *= 1.0f / (float)max(b1 - b0, 1);
    v += bias[o];
    const float* xr = x + n*64;
    #pragma unroll 8
    for (int i = 0; i < 64; i++) v += xr[i] * rs[i*64 + o];
    out[n*64 + o] = v;
}

extern "C" void kernel_launch(void* const* d_in, const int* in_sizes, int n_in,
                              void* d_out, int out_size, void* d_ws, size_t ws_size,
                              hipStream_t stream) {
    const float* x      = (const float*)d_in[0];
    const int*   ei     = (const int*)d_in[1];
    const float* pseudo = (const float*)d_in[2];
    const float* weight = (const float*)d_in[3];
    const float* root   = (const float*)d_in[4];
    const float* bias   = (const float*)d_in[5];
    float* out = (float*)d_out;
    char* ws = (char*)d_ws;

    unsigned short* msg    = (unsigned short*)(ws + 0);         // 20,480,000
    unsigned short* xg     = (unsigned short*)(ws + 20480000);  // 20,480,000
    float*          basisg = (float*)(ws + 40960000);           //  5,120,000
    int*            dsti   = (int*)(ws + 46080000);             //    640,000
    int*            degi   = (int*)(ws + 46720000);             //     80,000
    int*            cntp   = (int*)(ws + 46800000);             //      8,192
    int*            curp   = (int*)(ws + 46808192);             //      8,192
    int*            off    = (int*)(ws + 46816384);             //        512
    int*            rowoff = (int*)(ws + 46816896);             //     81,920 (20480 ints)
    int*            rposa  = (int*)(ws + 46898816);             //    640,000
    unsigned short* wfg    = (unsigned short*)(ws + 47538816);  //  4,194,304 -> ~51.7 MB

    // zero degi + cntp + curp (contiguous)
    hipMemsetAsync(ws + 46720000, 0, 96384, stream);

    k_count <<<(NE + 255)/256, 256, 0, stream>>>(pseudo, ei, cntp, degi, rposa);
    k_scans <<<2, 1024, 0, stream>>>(cntp, off, degi, rowoff);
    k_prep  <<<625 + 128, 256, 0, stream>>>(x, ei, pseudo, off, curp, rowoff, rposa,
                                            weight, xg, basisg, dsti, wfg);
    k_main  <<<64*2*CPB, 256, 0, stream>>>(wfg, off, xg, basisg, dsti, msg);
    k_final2<<<NN/4, 256, 0, stream>>>(x, root, bias, msg, rowoff, out);
}